// Round 16
// baseline (184.731 us; speedup 1.0000x reference)
//
#include <hip/hip_runtime.h>
#include <math.h>

#define NN 50000
#define NE 800000
#define ESLICE2 400128   // 1563 blocks * 256 threads; 2 slices cover NE

typedef __bf16 bf16x8 __attribute__((ext_vector_type(8)));
typedef __bf16 bf16x4 __attribute__((ext_vector_type(4)));
typedef float f32x4 __attribute__((ext_vector_type(4)));

__device__ __forceinline__ void gload16(const void* g, void* l){
  __builtin_amdgcn_global_load_lds((const __attribute__((address_space(1))) void*)g,
                                   (__attribute__((address_space(3))) void*)l, 16, 0, 0);
}

// ---------------- zero cur ----------------

__global__ __launch_bounds__(256)
void k_zero(int* __restrict__ p){
  const int i = blockIdx.x * 256 + threadIdx.x;
  if (i < NN) p[i] = 0;
}

// ---------------- merged rank + conversions ----------------

__global__ __launch_bounds__(256)
void rank_conv(const int* __restrict__ erow, int* __restrict__ cnt, int* __restrict__ pos,
               const float* __restrict__ x, const float* __restrict__ W1,
               const float* __restrict__ W2, __bf16* __restrict__ xb,
               __bf16* __restrict__ W1b, __bf16* __restrict__ W2b){
  const int b = blockIdx.x;
  if (b < 1563){
    const int t = b * 256 + threadIdx.x;
    #pragma unroll
    for (int k = 0; k < 2; ++k){
      const int e = t + k * ESLICE2;
      if (e < NE){
        const int r = erow[e];
        pos[e] = atomicAdd(&cnt[r], 1);
      }
    }
    return;
  }
  const int cb = b - 1563;
  const float* src; __bf16* dst; int q, M, K, Kp;
  if (cb < 15640){ src = x;  dst = xb;  q = cb * 256 + threadIdx.x; M = NN;  K = 300; Kp = 320; }
  else if (cb < 15720){ src = W1; dst = W1b; q = (cb - 15640) * 256 + threadIdx.x; M = 256; K = 300; Kp = 320; }
  else { src = W2; dst = W2b; q = (cb - 15720) * 256 + threadIdx.x; M = 128; K = 256; Kp = 256; }
  const int perRow = Kp >> 2;
  const int r = q / perRow;
  const int k = (q - r * perRow) << 2;
  float4 v = make_float4(0.f, 0.f, 0.f, 0.f);
  if (r < M && k < K) v = *(const float4*)(src + (size_t)r * K + k);   // K % 4 == 0
  bf16x4 o;
  o[0] = (__bf16)v.x; o[1] = (__bf16)v.y; o[2] = (__bf16)v.z; o[3] = (__bf16)v.w;
  *(bf16x4*)(dst + (size_t)r * Kp + k) = o;
}

// ---------------- scans ----------------

__global__ __launch_bounds__(256)
void k_scan1(const int* __restrict__ cnt, int* __restrict__ rs, int* __restrict__ part, int n){
  const int t = threadIdx.x, b = blockIdx.x;
  const int i = b * 256 + t;
  int v = (i < n) ? cnt[i] : 0;
  const int lane = t & 63, w = t >> 6;
  int s = v;
  #pragma unroll
  for (int d = 1; d < 64; d <<= 1){ int u = __shfl_up(s, d); if (lane >= d) s += u; }
  __shared__ int wsum[4];
  if (lane == 63) wsum[w] = s;
  __syncthreads();
  int add = 0;
  #pragma unroll
  for (int k = 0; k < 4; ++k) if (k < w) add += wsum[k];
  s += add;
  if (i < n) rs[i + 1] = s;
  if (t == 255) part[b] = s;
}

__global__ __launch_bounds__(256)
void k_scan3(int* __restrict__ rs, const int* __restrict__ part, int n){
  const int t = threadIdx.x, b = blockIdx.x;
  int v = (t < b) ? part[t] : 0;                 // b <= 195 < 256
  const int lane = t & 63, w = t >> 6;
  #pragma unroll
  for (int m = 32; m; m >>= 1) v += __shfl_xor(v, m);
  __shared__ int wsum[4];
  if (lane == 0) wsum[w] = v;
  __syncthreads();
  const int add = wsum[0] + wsum[1] + wsum[2] + wsum[3];
  const int i = b * 256 + t;
  if (i < n) rs[i + 1] += add;
  if (b == 0 && t == 0) rs[0] = 0;
}

// ---------------- merged scatter + GEMM1 ----------------

template<int KT, int LGN>
__global__ __launch_bounds__(256)
void scat_gemm(const int* __restrict__ erow, const int* __restrict__ ecol,
               const float* __restrict__ evalv, const int* __restrict__ rs,
               const int* __restrict__ pos, int2* __restrict__ ecv,
               const __bf16* __restrict__ A, const __bf16* __restrict__ B,
               __bf16* __restrict__ C, int ld, int N){
  __shared__ char ldsbuf[49152];
  const int tid = threadIdx.x;
  if (blockIdx.x < 1563){
    const int t = blockIdx.x * 256 + tid;
    #pragma unroll
    for (int k = 0; k < 2; ++k){
      const int e = t + k * ESLICE2;
      if (e < NE){
        const int r = erow[e];
        const int p = rs[r] + pos[e];
        ecv[p] = make_int2(ecol[e], __float_as_int(evalv[e]));
      }
    }
    return;
  }
  const int lane = tid & 63;
  const int L = blockIdx.x - 1563;
  const int bmt = (L & 7) + ((L >> (3 + LGN)) << 3);
  if (bmt >= 391) return;
  const int bm = bmt * 128;
  const int bn = ((L >> 3) & ((1 << LGN) - 1)) * 64;
  const int wr = (tid >> 7) & 1;
  const int wc = (tid >> 6) & 1;

  f32x4 acc[4][2];
  #pragma unroll
  for (int i = 0; i < 4; ++i)
    #pragma unroll
    for (int j = 0; j < 2; ++j) acc[i][j] = (f32x4){0.f, 0.f, 0.f, 0.f};

  auto stage = [&](int kt, int sel){
    char* lb = ldsbuf + sel * 24576;
    #pragma unroll
    for (int i = 0; i < 4; ++i){
      const int d = i * 4096 + tid * 16;
      const int row = d >> 7;
      const int colb = (d & 127) ^ ((row & 7) << 4);
      const __bf16* gp = A + (size_t)(bm + row) * ld + kt * 64 + (colb >> 1);
      gload16(gp, lb + i * 4096 + (tid & 192) * 16);
    }
    #pragma unroll
    for (int i = 0; i < 2; ++i){
      const int d = i * 4096 + tid * 16;
      const int row = d >> 7;
      const int colb = (d & 127) ^ ((row & 7) << 4);
      const __bf16* gp = B + (size_t)(bn + row) * ld + kt * 64 + (colb >> 1);
      gload16(gp, lb + 16384 + i * 4096 + (tid & 192) * 16);
    }
  };

  auto compute = [&](int sel){
    const char* lA = ldsbuf + sel * 24576;
    const char* lB = lA + 16384;
    #pragma unroll
    for (int c = 0; c < 2; ++c){
      bf16x8 av[4], bv[2];
      #pragma unroll
      for (int i = 0; i < 4; ++i){
        const int row = wr * 64 + i * 16 + (lane & 15);
        const int colb = (c * 64 + ((lane >> 4) << 4)) ^ ((row & 7) << 4);
        av[i] = *(const bf16x8*)(lA + row * 128 + colb);
      }
      #pragma unroll
      for (int j = 0; j < 2; ++j){
        const int row = wc * 32 + j * 16 + (lane & 15);
        const int colb = (c * 64 + ((lane >> 4) << 4)) ^ ((row & 7) << 4);
        bv[j] = *(const bf16x8*)(lB + row * 128 + colb);
      }
      #pragma unroll
      for (int i = 0; i < 4; ++i)
        #pragma unroll
        for (int j = 0; j < 2; ++j)
          acc[i][j] = __builtin_amdgcn_mfma_f32_16x16x32_bf16(av[i], bv[j], acc[i][j], 0, 0, 0);
    }
  };

  stage(0, 0);
  for (int kt = 0; kt < KT; ++kt){
    __syncthreads();
    if (kt + 1 < KT) stage(kt + 1, (kt + 1) & 1);
    compute(kt & 1);
  }

  __syncthreads();
  float* lw = (float*)ldsbuf;
  #pragma unroll
  for (int i = 0; i < 4; ++i)
    #pragma unroll
    for (int j = 0; j < 2; ++j)
      #pragma unroll
      for (int r = 0; r < 4; ++r){
        const int row = wr * 64 + i * 16 + ((lane >> 4) << 2) + r;
        const int col = wc * 32 + j * 16 + (lane & 15);
        lw[row * 68 + col] = acc[i][j][r];
      }
  __syncthreads();
  #pragma unroll
  for (int p = 0; p < 4; ++p){
    const int row = p * 32 + (tid >> 3);
    const int col8 = (tid & 7) * 8;
    const float4 v0 = *(const float4*)&lw[row * 68 + col8];
    const float4 v1 = *(const float4*)&lw[row * 68 + col8 + 4];
    bf16x8 o;
    o[0] = (__bf16)v0.x; o[1] = (__bf16)v0.y; o[2] = (__bf16)v0.z; o[3] = (__bf16)v0.w;
    o[4] = (__bf16)v1.x; o[5] = (__bf16)v1.y; o[6] = (__bf16)v1.z; o[7] = (__bf16)v1.w;
    *(bf16x8*)(C + (size_t)(bm + row) * N + bn + col8) = o;
  }
}

// ---------------- plain GEMM (layer 2) ----------------

template<int KT, int LGN>
__global__ __launch_bounds__(256)
void gemm_bf16(const __bf16* __restrict__ A, const __bf16* __restrict__ B,
               __bf16* __restrict__ C, int ld, int N){
  __shared__ char ldsbuf[49152];
  const int tid = threadIdx.x;
  const int lane = tid & 63;
  const int L = blockIdx.x;
  const int bmt = (L & 7) + ((L >> (3 + LGN)) << 3);
  if (bmt >= 391) return;
  const int bm = bmt * 128;
  const int bn = ((L >> 3) & ((1 << LGN) - 1)) * 64;
  const int wr = (tid >> 7) & 1;
  const int wc = (tid >> 6) & 1;

  f32x4 acc[4][2];
  #pragma unroll
  for (int i = 0; i < 4; ++i)
    #pragma unroll
    for (int j = 0; j < 2; ++j) acc[i][j] = (f32x4){0.f, 0.f, 0.f, 0.f};

  auto stage = [&](int kt, int sel){
    char* lb = ldsbuf + sel * 24576;
    #pragma unroll
    for (int i = 0; i < 4; ++i){
      const int d = i * 4096 + tid * 16;
      const int row = d >> 7;
      const int colb = (d & 127) ^ ((row & 7) << 4);
      const __bf16* gp = A + (size_t)(bm + row) * ld + kt * 64 + (colb >> 1);
      gload16(gp, lb + i * 4096 + (tid & 192) * 16);
    }
    #pragma unroll
    for (int i = 0; i < 2; ++i){
      const int d = i * 4096 + tid * 16;
      const int row = d >> 7;
      const int colb = (d & 127) ^ ((row & 7) << 4);
      const __bf16* gp = B + (size_t)(bn + row) * ld + kt * 64 + (colb >> 1);
      gload16(gp, lb + 16384 + i * 4096 + (tid & 192) * 16);
    }
  };

  auto compute = [&](int sel){
    const char* lA = ldsbuf + sel * 24576;
    const char* lB = lA + 16384;
    #pragma unroll
    for (int c = 0; c < 2; ++c){
      bf16x8 av[4], bv[2];
      #pragma unroll
      for (int i = 0; i < 4; ++i){
        const int row = wr * 64 + i * 16 + (lane & 15);
        const int colb = (c * 64 + ((lane >> 4) << 4)) ^ ((row & 7) << 4);
        av[i] = *(const bf16x8*)(lA + row * 128 + colb);
      }
      #pragma unroll
      for (int j = 0; j < 2; ++j){
        const int row = wc * 32 + j * 16 + (lane & 15);
        const int colb = (c * 64 + ((lane >> 4) << 4)) ^ ((row & 7) << 4);
        bv[j] = *(const bf16x8*)(lB + row * 128 + colb);
      }
      #pragma unroll
      for (int i = 0; i < 4; ++i)
        #pragma unroll
        for (int j = 0; j < 2; ++j)
          acc[i][j] = __builtin_amdgcn_mfma_f32_16x16x32_bf16(av[i], bv[j], acc[i][j], 0, 0, 0);
    }
  };

  stage(0, 0);
  for (int kt = 0; kt < KT; ++kt){
    __syncthreads();
    if (kt + 1 < KT) stage(kt + 1, (kt + 1) & 1);
    compute(kt & 1);
  }

  __syncthreads();
  float* lw = (float*)ldsbuf;
  #pragma unroll
  for (int i = 0; i < 4; ++i)
    #pragma unroll
    for (int j = 0; j < 2; ++j)
      #pragma unroll
      for (int r = 0; r < 4; ++r){
        const int row = wr * 64 + i * 16 + ((lane >> 4) << 2) + r;
        const int col = wc * 32 + j * 16 + (lane & 15);
        lw[row * 68 + col] = acc[i][j][r];
      }
  __syncthreads();
  #pragma unroll
  for (int p = 0; p < 4; ++p){
    const int row = p * 32 + (tid >> 3);
    const int col8 = (tid & 7) * 8;
    const float4 v0 = *(const float4*)&lw[row * 68 + col8];
    const float4 v1 = *(const float4*)&lw[row * 68 + col8 + 4];
    bf16x8 o;
    o[0] = (__bf16)v0.x; o[1] = (__bf16)v0.y; o[2] = (__bf16)v0.z; o[3] = (__bf16)v0.w;
    o[4] = (__bf16)v1.x; o[5] = (__bf16)v1.y; o[6] = (__bf16)v1.z; o[7] = (__bf16)v1.w;
    *(bf16x8*)(C + (size_t)(bm + row) * N + bn + col8) = o;
  }
}

// ---------------- SpMM layer 1 (two 128-ch halves, tail-split groups) ----------------
// blocks [0,12500) ch0=0, [12500,25000) ch0=128; quarter q owns edges idx%4==q;
// 8 gathers in flight; a[8] (VGPR-frugal). Full 16-edge groups UNGUARDED + 1 tail.

#define SPMM1_GROUP(GUARD)                                                    \
  {                                                                           \
    int cc[4]; float vv[4];                                                   \
    _Pragma("unroll")                                                         \
    for (int u = 0; u < 4; ++u){                                              \
      const int idx = j16 + quar + 4 * u;                                     \
      cc[u] = __shfl(cv.x, idx);                                              \
      vv[u] = __int_as_float(__shfl(cv.y, idx));                              \
      if (GUARD && idx >= m){ cc[u] = 0; vv[u] = 0.f; }                       \
    }                                                                         \
    bf16x8 h[4];                                                              \
    _Pragma("unroll")                                                         \
    for (int u = 0; u < 4; ++u)                                               \
      h[u] = *(const bf16x8*)(Hb + ((size_t)cc[u] << 8));                     \
    _Pragma("unroll")                                                         \
    for (int u = 0; u < 4; ++u){                                              \
      _Pragma("unroll")                                                       \
      for (int k = 0; k < 8; ++k)                                             \
        a[k] = fmaf(vv[u], (float)h[u][k], a[k]);                             \
    }                                                                         \
  }

__global__ __launch_bounds__(256)
void spmm_relu_b16(const int2* __restrict__ ecv, const int* __restrict__ start,
                   const __bf16* __restrict__ H, const float* __restrict__ bias,
                   __bf16* __restrict__ out){
  const int half = (blockIdx.x >= 12500) ? 1 : 0;
  const int bb = blockIdx.x - half * 12500;
  const int ch0 = half * 128;
  const int w = (bb * 256 + threadIdx.x) >> 6;
  const int lane = threadIdx.x & 63;
  const int quar = lane >> 4, sl = lane & 15;
  if (w >= NN) return;
  const int s = start[w], e = start[w + 1];
  const __bf16* Hb = H + ch0 + sl * 8;
  float a[8];
  #pragma unroll
  for (int k = 0; k < 8; ++k) a[k] = 0.f;
  for (int base = s; base < e; base += 64){
    int2 cv = make_int2(0, 0);
    if (base + lane < e) cv = ecv[base + lane];
    const int m = min(64, e - base);
    const int mf = m & ~15;
    for (int j16 = 0; j16 < mf; j16 += 16){
      SPMM1_GROUP(0)
    }
    if (mf < m){
      const int j16 = mf;
      SPMM1_GROUP(1)
    }
  }
  #pragma unroll
  for (int k = 0; k < 8; ++k){
    a[k] += __shfl_xor(a[k], 32);
    a[k] += __shfl_xor(a[k], 16);
  }
  const float4 b0 = *(const float4*)(bias + ch0 + sl * 8);
  const float4 b1 = *(const float4*)(bias + ch0 + sl * 8 + 4);
  bf16x8 o;
  o[0] = (__bf16)fmaxf(a[0] + b0.x, 0.f);
  o[1] = (__bf16)fmaxf(a[1] + b0.y, 0.f);
  o[2] = (__bf16)fmaxf(a[2] + b0.z, 0.f);
  o[3] = (__bf16)fmaxf(a[3] + b0.w, 0.f);
  o[4] = (__bf16)fmaxf(a[4] + b1.x, 0.f);
  o[5] = (__bf16)fmaxf(a[5] + b1.y, 0.f);
  o[6] = (__bf16)fmaxf(a[6] + b1.z, 0.f);
  o[7] = (__bf16)fmaxf(a[7] + b1.w, 0.f);
  if (quar == 0) *(bf16x8*)(out + (size_t)w * 256 + ch0 + sl * 8) = o;
}

// ---------------- SpMM layer 2 (128ch, tail-split) + bias + L2 normalize ----------------

#define SPMM2_GROUP(GUARD)                                                    \
  {                                                                           \
    int cc[4]; float vv[4];                                                   \
    _Pragma("unroll")                                                         \
    for (int u = 0; u < 4; ++u){                                              \
      const int idx = j16 + quar + 4 * u;                                     \
      cc[u] = __shfl(cv.x, idx);                                              \
      vv[u] = __int_as_float(__shfl(cv.y, idx));                              \
      if (GUARD && idx >= m){ cc[u] = 0; vv[u] = 0.f; }                       \
    }                                                                         \
    bf16x8 h[4];                                                              \
    _Pragma("unroll")                                                         \
    for (int u = 0; u < 4; ++u)                                               \
      h[u] = *(const bf16x8*)(Hb + ((size_t)cc[u] << 7));                     \
    _Pragma("unroll")                                                         \
    for (int u = 0; u < 4; ++u){                                              \
      _Pragma("unroll")                                                       \
      for (int k = 0; k < 8; ++k)                                             \
        a[k] = fmaf(vv[u], (float)h[u][k], a[k]);                             \
    }                                                                         \
  }

__global__ __launch_bounds__(256)
void spmm_bias_norm_b16(const int2* __restrict__ ecv, const int* __restrict__ start,
                        const __bf16* __restrict__ H, const float* __restrict__ bias,
                        float* __restrict__ out){
  const int w = (blockIdx.x * 256 + threadIdx.x) >> 6;
  const int lane = threadIdx.x & 63;
  const int quar = lane >> 4, sl = lane & 15;
  if (w >= NN) return;
  const int s = start[w], e = start[w + 1];
  const __bf16* Hb = H + sl * 8;
  float a[8];
  #pragma unroll
  for (int k = 0; k < 8; ++k) a[k] = 0.f;
  for (int base = s; base < e; base += 64){
    int2 cv = make_int2(0, 0);
    if (base + lane < e) cv = ecv[base + lane];
    const int m = min(64, e - base);
    const int mf = m & ~15;
    for (int j16 = 0; j16 < mf; j16 += 16){
      SPMM2_GROUP(0)
    }
    if (mf < m){
      const int j16 = mf;
      SPMM2_GROUP(1)
    }
  }
  #pragma unroll
  for (int k = 0; k < 8; ++k){
    a[k] += __shfl_xor(a[k], 32);
    a[k] += __shfl_xor(a[k], 16);
  }
  const float4 b0 = *(const float4*)(bias + sl * 8);
  const float4 b1 = *(const float4*)(bias + sl * 8 + 4);
  float f[8];
  f[0] = a[0] + b0.x; f[1] = a[1] + b0.y; f[2] = a[2] + b0.z; f[3] = a[3] + b0.w;
  f[4] = a[4] + b1.x; f[5] = a[5] + b1.y; f[6] = a[6] + b1.z; f[7] = a[7] + b1.w;
  float ss = 0.f;
  #pragma unroll
  for (int k = 0; k < 8; ++k) ss = fmaf(f[k], f[k], ss);
  #pragma unroll
  for (int m2 = 1; m2 < 16; m2 <<= 1) ss += __shfl_xor(ss, m2);
  const float inv = 1.f / fmaxf(sqrtf(ss), 1e-12f);
  if (quar == 0){
    float4 o0 = make_float4(f[0] * inv, f[1] * inv, f[2] * inv, f[3] * inv);
    float4 o1 = make_float4(f[4] * inv, f[5] * inv, f[6] * inv, f[7] * inv);
    *(float4*)(out + (size_t)w * 128 + sl * 8) = o0;
    *(float4*)(out + (size_t)w * 128 + sl * 8 + 4) = o1;
  }
}

// ---------------- launch ----------------
// ws layout (bytes):
//  xb  @ 0          [50048][320] bf16 = 32,030,720
//  W1b @ 32030720   [256][320]  bf16 =    163,840
//  W2b @ 32194560   [128][256]  bf16 =     65,536
//  h1  @ 32260096   [50048][256]bf16 = 25,624,576
//  h2  @ 57884672   [50048][256]bf16 = 25,624,576
//  h3  @ 83509248   [50048][128]bf16 = 12,812,288
//  ecv @ 96321536   800000 int2      =  6,400,000
//  rs  @ 102721536  50001 int        =    200,016
//  part@ 102921552  ~200 int (pad)
//  cur @ 102922368  50000 int        =    200,000
//  pos @ 103122368  800000 int       =  3,200,000   total ~106.3 MB

extern "C" void kernel_launch(void* const* d_in, const int* in_sizes, int n_in,
                              void* d_out, int out_size, void* d_ws, size_t ws_size,
                              hipStream_t stream){
  const float* x    = (const float*)d_in[0];
  const int*   erow = (const int*)d_in[1];
  const int*   ecol = (const int*)d_in[2];
  const float* evalv= (const float*)d_in[3];
  const float* W1   = (const float*)d_in[4];
  const float* b1   = (const float*)d_in[5];
  const float* W2   = (const float*)d_in[6];
  const float* b2   = (const float*)d_in[7];
  float* out = (float*)d_out;

  char* ws = (char*)d_ws;
  __bf16* xb  = (__bf16*)(ws);
  __bf16* W1b = (__bf16*)(ws + 32030720);
  __bf16* W2b = (__bf16*)(ws + 32194560);
  __bf16* h1  = (__bf16*)(ws + 32260096);
  __bf16* h2  = (__bf16*)(ws + 57884672);
  __bf16* h3  = (__bf16*)(ws + 83509248);
  int2*   ecv = (int2*)(ws + 96321536);
  int*    rs  = (int*)(ws + 102721536);
  int*    part= (int*)(ws + 102921552);
  int*    cur = (int*)(ws + 102922368);
  int*    pos = (int*)(ws + 103122368);   // dedicated storage (no alias)

  // 1) zero cur
  k_zero<<<196, 256, 0, stream>>>(cur);
  // 2) rank (latency-bound) overlapped with x/W conversions (BW-bound)
  rank_conv<<<17315, 256, 0, stream>>>(erow, cur, pos, x, W1, W2, xb, W1b, W2b);
  // 3-4) scan
  k_scan1<<<196, 256, 0, stream>>>(cur, rs, part, NN);
  k_scan3<<<196, 256, 0, stream>>>(rs, part, NN);
  // 5) scatter overlapped with gemm1 (h1 = bf16(xb @ W1b^T))
  scat_gemm<5, 2><<<3131, 256, 0, stream>>>(erow, ecol, evalv, rs, pos, ecv,
                                            xb, W1b, h1, 320, 256);
  // 6) h2 = bf16(relu(A*h1 + b1)), two 128-ch halves, tail-split groups
  spmm_relu_b16<<<25000, 256, 0, stream>>>(ecv, rs, h1, b1, h2);
  // 7) h3 = bf16(h2 @ W2b^T)
  gemm_bf16<4, 1><<<784, 256, 0, stream>>>(h2, W2b, h3, 256, 128);
  // 8) out = l2norm(A*h3 + b2)
  spmm_bias_norm_b16<<<12500, 256, 0, stream>>>(ecv, rs, h3, b2, out);
}

// Round 17
// 182.080 us; speedup vs baseline: 1.0146x; 1.0146x over previous
//
#include <hip/hip_runtime.h>
#include <math.h>

#define NN 50000
#define NE 800000
#define ESLICE2 400128   // 1563 blocks * 256 threads; 2 slices cover NE

typedef __bf16 bf16x8 __attribute__((ext_vector_type(8)));
typedef __bf16 bf16x4 __attribute__((ext_vector_type(4)));
typedef float f32x4 __attribute__((ext_vector_type(4)));

__device__ __forceinline__ void gload16(const void* g, void* l){
  __builtin_amdgcn_global_load_lds((const __attribute__((address_space(1))) void*)g,
                                   (__attribute__((address_space(3))) void*)l, 16, 0, 0);
}

// ---------------- zero cur ----------------

__global__ __launch_bounds__(256)
void k_zero(int* __restrict__ p){
  const int i = blockIdx.x * 256 + threadIdx.x;
  if (i < NN) p[i] = 0;
}

// ---------------- merged rank + conversions ----------------

__global__ __launch_bounds__(256)
void rank_conv(const int* __restrict__ erow, int* __restrict__ cnt, int* __restrict__ pos,
               const float* __restrict__ x, const float* __restrict__ W1,
               const float* __restrict__ W2, __bf16* __restrict__ xb,
               __bf16* __restrict__ W1b, __bf16* __restrict__ W2b){
  const int b = blockIdx.x;
  if (b < 1563){
    const int t = b * 256 + threadIdx.x;
    #pragma unroll
    for (int k = 0; k < 2; ++k){
      const int e = t + k * ESLICE2;
      if (e < NE){
        const int r = erow[e];
        pos[e] = atomicAdd(&cnt[r], 1);
      }
    }
    return;
  }
  const int cb = b - 1563;
  const float* src; __bf16* dst; int q, M, K, Kp;
  if (cb < 15640){ src = x;  dst = xb;  q = cb * 256 + threadIdx.x; M = NN;  K = 300; Kp = 320; }
  else if (cb < 15720){ src = W1; dst = W1b; q = (cb - 15640) * 256 + threadIdx.x; M = 256; K = 300; Kp = 320; }
  else { src = W2; dst = W2b; q = (cb - 15720) * 256 + threadIdx.x; M = 128; K = 256; Kp = 256; }
  const int perRow = Kp >> 2;
  const int r = q / perRow;
  const int k = (q - r * perRow) << 2;
  float4 v = make_float4(0.f, 0.f, 0.f, 0.f);
  if (r < M && k < K) v = *(const float4*)(src + (size_t)r * K + k);   // K % 4 == 0
  bf16x4 o;
  o[0] = (__bf16)v.x; o[1] = (__bf16)v.y; o[2] = (__bf16)v.z; o[3] = (__bf16)v.w;
  *(bf16x4*)(dst + (size_t)r * Kp + k) = o;
}

// ---------------- scans ----------------

__global__ __launch_bounds__(256)
void k_scan1(const int* __restrict__ cnt, int* __restrict__ rs, int* __restrict__ part, int n){
  const int t = threadIdx.x, b = blockIdx.x;
  const int i = b * 256 + t;
  int v = (i < n) ? cnt[i] : 0;
  const int lane = t & 63, w = t >> 6;
  int s = v;
  #pragma unroll
  for (int d = 1; d < 64; d <<= 1){ int u = __shfl_up(s, d); if (lane >= d) s += u; }
  __shared__ int wsum[4];
  if (lane == 63) wsum[w] = s;
  __syncthreads();
  int add = 0;
  #pragma unroll
  for (int k = 0; k < 4; ++k) if (k < w) add += wsum[k];
  s += add;
  if (i < n) rs[i + 1] = s;
  if (t == 255) part[b] = s;
}

__global__ __launch_bounds__(256)
void k_scan3(int* __restrict__ rs, const int* __restrict__ part, int n){
  const int t = threadIdx.x, b = blockIdx.x;
  int v = (t < b) ? part[t] : 0;                 // b <= 195 < 256
  const int lane = t & 63, w = t >> 6;
  #pragma unroll
  for (int m = 32; m; m >>= 1) v += __shfl_xor(v, m);
  __shared__ int wsum[4];
  if (lane == 0) wsum[w] = v;
  __syncthreads();
  const int add = wsum[0] + wsum[1] + wsum[2] + wsum[3];
  const int i = b * 256 + t;
  if (i < n) rs[i + 1] += add;
  if (b == 0 && t == 0) rs[0] = 0;
}

// ---------------- merged scatter + GEMM1 ----------------

template<int KT, int LGN>
__global__ __launch_bounds__(256)
void scat_gemm(const int* __restrict__ erow, const int* __restrict__ ecol,
               const float* __restrict__ evalv, const int* __restrict__ rs,
               const int* __restrict__ pos, int2* __restrict__ ecv,
               const __bf16* __restrict__ A, const __bf16* __restrict__ B,
               __bf16* __restrict__ C, int ld, int N){
  __shared__ char ldsbuf[49152];
  const int tid = threadIdx.x;
  if (blockIdx.x < 1563){
    const int t = blockIdx.x * 256 + tid;
    #pragma unroll
    for (int k = 0; k < 2; ++k){
      const int e = t + k * ESLICE2;
      if (e < NE){
        const int r = erow[e];
        const int p = rs[r] + pos[e];
        ecv[p] = make_int2(ecol[e], __float_as_int(evalv[e]));
      }
    }
    return;
  }
  const int lane = tid & 63;
  const int L = blockIdx.x - 1563;
  const int bmt = (L & 7) + ((L >> (3 + LGN)) << 3);
  if (bmt >= 391) return;
  const int bm = bmt * 128;
  const int bn = ((L >> 3) & ((1 << LGN) - 1)) * 64;
  const int wr = (tid >> 7) & 1;
  const int wc = (tid >> 6) & 1;

  f32x4 acc[4][2];
  #pragma unroll
  for (int i = 0; i < 4; ++i)
    #pragma unroll
    for (int j = 0; j < 2; ++j) acc[i][j] = (f32x4){0.f, 0.f, 0.f, 0.f};

  auto stage = [&](int kt, int sel){
    char* lb = ldsbuf + sel * 24576;
    #pragma unroll
    for (int i = 0; i < 4; ++i){
      const int d = i * 4096 + tid * 16;
      const int row = d >> 7;
      const int colb = (d & 127) ^ ((row & 7) << 4);
      const __bf16* gp = A + (size_t)(bm + row) * ld + kt * 64 + (colb >> 1);
      gload16(gp, lb + i * 4096 + (tid & 192) * 16);
    }
    #pragma unroll
    for (int i = 0; i < 2; ++i){
      const int d = i * 4096 + tid * 16;
      const int row = d >> 7;
      const int colb = (d & 127) ^ ((row & 7) << 4);
      const __bf16* gp = B + (size_t)(bn + row) * ld + kt * 64 + (colb >> 1);
      gload16(gp, lb + 16384 + i * 4096 + (tid & 192) * 16);
    }
  };

  auto compute = [&](int sel){
    const char* lA = ldsbuf + sel * 24576;
    const char* lB = lA + 16384;
    #pragma unroll
    for (int c = 0; c < 2; ++c){
      bf16x8 av[4], bv[2];
      #pragma unroll
      for (int i = 0; i < 4; ++i){
        const int row = wr * 64 + i * 16 + (lane & 15);
        const int colb = (c * 64 + ((lane >> 4) << 4)) ^ ((row & 7) << 4);
        av[i] = *(const bf16x8*)(lA + row * 128 + colb);
      }
      #pragma unroll
      for (int j = 0; j < 2; ++j){
        const int row = wc * 32 + j * 16 + (lane & 15);
        const int colb = (c * 64 + ((lane >> 4) << 4)) ^ ((row & 7) << 4);
        bv[j] = *(const bf16x8*)(lB + row * 128 + colb);
      }
      #pragma unroll
      for (int i = 0; i < 4; ++i)
        #pragma unroll
        for (int j = 0; j < 2; ++j)
          acc[i][j] = __builtin_amdgcn_mfma_f32_16x16x32_bf16(av[i], bv[j], acc[i][j], 0, 0, 0);
    }
  };

  stage(0, 0);
  for (int kt = 0; kt < KT; ++kt){
    __syncthreads();
    if (kt + 1 < KT) stage(kt + 1, (kt + 1) & 1);
    compute(kt & 1);
  }

  __syncthreads();
  float* lw = (float*)ldsbuf;
  #pragma unroll
  for (int i = 0; i < 4; ++i)
    #pragma unroll
    for (int j = 0; j < 2; ++j)
      #pragma unroll
      for (int r = 0; r < 4; ++r){
        const int row = wr * 64 + i * 16 + ((lane >> 4) << 2) + r;
        const int col = wc * 32 + j * 16 + (lane & 15);
        lw[row * 68 + col] = acc[i][j][r];
      }
  __syncthreads();
  #pragma unroll
  for (int p = 0; p < 4; ++p){
    const int row = p * 32 + (tid >> 3);
    const int col8 = (tid & 7) * 8;
    const float4 v0 = *(const float4*)&lw[row * 68 + col8];
    const float4 v1 = *(const float4*)&lw[row * 68 + col8 + 4];
    bf16x8 o;
    o[0] = (__bf16)v0.x; o[1] = (__bf16)v0.y; o[2] = (__bf16)v0.z; o[3] = (__bf16)v0.w;
    o[4] = (__bf16)v1.x; o[5] = (__bf16)v1.y; o[6] = (__bf16)v1.z; o[7] = (__bf16)v1.w;
    *(bf16x8*)(C + (size_t)(bm + row) * N + bn + col8) = o;
  }
}

// ---------------- plain GEMM (layer 2) ----------------

template<int KT, int LGN>
__global__ __launch_bounds__(256)
void gemm_bf16(const __bf16* __restrict__ A, const __bf16* __restrict__ B,
               __bf16* __restrict__ C, int ld, int N){
  __shared__ char ldsbuf[49152];
  const int tid = threadIdx.x;
  const int lane = tid & 63;
  const int L = blockIdx.x;
  const int bmt = (L & 7) + ((L >> (3 + LGN)) << 3);
  if (bmt >= 391) return;
  const int bm = bmt * 128;
  const int bn = ((L >> 3) & ((1 << LGN) - 1)) * 64;
  const int wr = (tid >> 7) & 1;
  const int wc = (tid >> 6) & 1;

  f32x4 acc[4][2];
  #pragma unroll
  for (int i = 0; i < 4; ++i)
    #pragma unroll
    for (int j = 0; j < 2; ++j) acc[i][j] = (f32x4){0.f, 0.f, 0.f, 0.f};

  auto stage = [&](int kt, int sel){
    char* lb = ldsbuf + sel * 24576;
    #pragma unroll
    for (int i = 0; i < 4; ++i){
      const int d = i * 4096 + tid * 16;
      const int row = d >> 7;
      const int colb = (d & 127) ^ ((row & 7) << 4);
      const __bf16* gp = A + (size_t)(bm + row) * ld + kt * 64 + (colb >> 1);
      gload16(gp, lb + i * 4096 + (tid & 192) * 16);
    }
    #pragma unroll
    for (int i = 0; i < 2; ++i){
      const int d = i * 4096 + tid * 16;
      const int row = d >> 7;
      const int colb = (d & 127) ^ ((row & 7) << 4);
      const __bf16* gp = B + (size_t)(bn + row) * ld + kt * 64 + (colb >> 1);
      gload16(gp, lb + 16384 + i * 4096 + (tid & 192) * 16);
    }
  };

  auto compute = [&](int sel){
    const char* lA = ldsbuf + sel * 24576;
    const char* lB = lA + 16384;
    #pragma unroll
    for (int c = 0; c < 2; ++c){
      bf16x8 av[4], bv[2];
      #pragma unroll
      for (int i = 0; i < 4; ++i){
        const int row = wr * 64 + i * 16 + (lane & 15);
        const int colb = (c * 64 + ((lane >> 4) << 4)) ^ ((row & 7) << 4);
        av[i] = *(const bf16x8*)(lA + row * 128 + colb);
      }
      #pragma unroll
      for (int j = 0; j < 2; ++j){
        const int row = wc * 32 + j * 16 + (lane & 15);
        const int colb = (c * 64 + ((lane >> 4) << 4)) ^ ((row & 7) << 4);
        bv[j] = *(const bf16x8*)(lB + row * 128 + colb);
      }
      #pragma unroll
      for (int i = 0; i < 4; ++i)
        #pragma unroll
        for (int j = 0; j < 2; ++j)
          acc[i][j] = __builtin_amdgcn_mfma_f32_16x16x32_bf16(av[i], bv[j], acc[i][j], 0, 0, 0);
    }
  };

  stage(0, 0);
  for (int kt = 0; kt < KT; ++kt){
    __syncthreads();
    if (kt + 1 < KT) stage(kt + 1, (kt + 1) & 1);
    compute(kt & 1);
  }

  __syncthreads();
  float* lw = (float*)ldsbuf;
  #pragma unroll
  for (int i = 0; i < 4; ++i)
    #pragma unroll
    for (int j = 0; j < 2; ++j)
      #pragma unroll
      for (int r = 0; r < 4; ++r){
        const int row = wr * 64 + i * 16 + ((lane >> 4) << 2) + r;
        const int col = wc * 32 + j * 16 + (lane & 15);
        lw[row * 68 + col] = acc[i][j][r];
      }
  __syncthreads();
  #pragma unroll
  for (int p = 0; p < 4; ++p){
    const int row = p * 32 + (tid >> 3);
    const int col8 = (tid & 7) * 8;
    const float4 v0 = *(const float4*)&lw[row * 68 + col8];
    const float4 v1 = *(const float4*)&lw[row * 68 + col8 + 4];
    bf16x8 o;
    o[0] = (__bf16)v0.x; o[1] = (__bf16)v0.y; o[2] = (__bf16)v0.z; o[3] = (__bf16)v0.w;
    o[4] = (__bf16)v1.x; o[5] = (__bf16)v1.y; o[6] = (__bf16)v1.z; o[7] = (__bf16)v1.w;
    *(bf16x8*)(C + (size_t)(bm + row) * N + bn + col8) = o;
  }
}

// ---------------- SpMM layer 1 (r13 best: two 128-ch halves, one dispatch, plain) ------

__global__ __launch_bounds__(256)
void spmm_relu_b16(const int2* __restrict__ ecv, const int* __restrict__ start,
                   const __bf16* __restrict__ H, const float* __restrict__ bias,
                   __bf16* __restrict__ out){
  const int half = (blockIdx.x >= 12500) ? 1 : 0;
  const int bb = blockIdx.x - half * 12500;
  const int ch0 = half * 128;
  const int w = (bb * 256 + threadIdx.x) >> 6;
  const int lane = threadIdx.x & 63;
  const int quar = lane >> 4, sl = lane & 15;
  if (w >= NN) return;
  const int s = start[w], e = start[w + 1];
  float a[8];
  #pragma unroll
  for (int k = 0; k < 8; ++k) a[k] = 0.f;
  for (int base = s; base < e; base += 64){
    int2 cv = make_int2(0, 0);
    if (base + lane < e) cv = ecv[base + lane];
    const int m = min(64, e - base);
    for (int j2 = 0; 16 * j2 < m; ++j2){
      int cc[4]; float vv[4];
      #pragma unroll
      for (int u = 0; u < 4; ++u){
        const int idx = 16 * j2 + quar + 4 * u;
        cc[u] = __shfl(cv.x, idx);
        vv[u] = __int_as_float(__shfl(cv.y, idx));
        if (idx >= m){ cc[u] = 0; vv[u] = 0.f; }
      }
      bf16x8 h[4];
      #pragma unroll
      for (int u = 0; u < 4; ++u)
        h[u] = *(const bf16x8*)(H + (size_t)cc[u] * 256 + ch0 + sl * 8);
      #pragma unroll
      for (int u = 0; u < 4; ++u)
        #pragma unroll
        for (int k = 0; k < 8; ++k) a[k] = fmaf(vv[u], (float)h[u][k], a[k]);
    }
  }
  #pragma unroll
  for (int k = 0; k < 8; ++k){
    a[k] += __shfl_xor(a[k], 32);
    a[k] += __shfl_xor(a[k], 16);
  }
  const float4 b0 = *(const float4*)(bias + ch0 + sl * 8);
  const float4 b1 = *(const float4*)(bias + ch0 + sl * 8 + 4);
  bf16x8 o;
  o[0] = (__bf16)fmaxf(a[0] + b0.x, 0.f);
  o[1] = (__bf16)fmaxf(a[1] + b0.y, 0.f);
  o[2] = (__bf16)fmaxf(a[2] + b0.z, 0.f);
  o[3] = (__bf16)fmaxf(a[3] + b0.w, 0.f);
  o[4] = (__bf16)fmaxf(a[4] + b1.x, 0.f);
  o[5] = (__bf16)fmaxf(a[5] + b1.y, 0.f);
  o[6] = (__bf16)fmaxf(a[6] + b1.z, 0.f);
  o[7] = (__bf16)fmaxf(a[7] + b1.w, 0.f);
  if (quar == 0) *(bf16x8*)(out + (size_t)w * 256 + ch0 + sl * 8) = o;
}

// ---------------- SpMM layer 2 (r13 best: plain quarters) + bias + L2 normalize --------

__global__ __launch_bounds__(256)
void spmm_bias_norm_b16(const int2* __restrict__ ecv, const int* __restrict__ start,
                        const __bf16* __restrict__ H, const float* __restrict__ bias,
                        float* __restrict__ out){
  const int w = (blockIdx.x * 256 + threadIdx.x) >> 6;
  const int lane = threadIdx.x & 63;
  const int quar = lane >> 4, sl = lane & 15;
  if (w >= NN) return;
  const int s = start[w], e = start[w + 1];
  float a[8];
  #pragma unroll
  for (int k = 0; k < 8; ++k) a[k] = 0.f;
  for (int base = s; base < e; base += 64){
    int2 cv = make_int2(0, 0);
    if (base + lane < e) cv = ecv[base + lane];
    const int m = min(64, e - base);
    for (int j2 = 0; 16 * j2 < m; ++j2){
      int cc[4]; float vv[4];
      #pragma unroll
      for (int u = 0; u < 4; ++u){
        const int idx = 16 * j2 + quar + 4 * u;
        cc[u] = __shfl(cv.x, idx);
        vv[u] = __int_as_float(__shfl(cv.y, idx));
        if (idx >= m){ cc[u] = 0; vv[u] = 0.f; }
      }
      bf16x8 h[4];
      #pragma unroll
      for (int u = 0; u < 4; ++u)
        h[u] = *(const bf16x8*)(H + (size_t)cc[u] * 128 + sl * 8);
      #pragma unroll
      for (int u = 0; u < 4; ++u)
        #pragma unroll
        for (int k = 0; k < 8; ++k) a[k] = fmaf(vv[u], (float)h[u][k], a[k]);
    }
  }
  #pragma unroll
  for (int k = 0; k < 8; ++k){
    a[k] += __shfl_xor(a[k], 32);
    a[k] += __shfl_xor(a[k], 16);
  }
  const float4 b0 = *(const float4*)(bias + sl * 8);
  const float4 b1 = *(const float4*)(bias + sl * 8 + 4);
  float f[8];
  f[0] = a[0] + b0.x; f[1] = a[1] + b0.y; f[2] = a[2] + b0.z; f[3] = a[3] + b0.w;
  f[4] = a[4] + b1.x; f[5] = a[5] + b1.y; f[6] = a[6] + b1.z; f[7] = a[7] + b1.w;
  float ss = 0.f;
  #pragma unroll
  for (int k = 0; k < 8; ++k) ss = fmaf(f[k], f[k], ss);
  #pragma unroll
  for (int m2 = 1; m2 < 16; m2 <<= 1) ss += __shfl_xor(ss, m2);
  const float inv = 1.f / fmaxf(sqrtf(ss), 1e-12f);
  if (quar == 0){
    float4 o0 = make_float4(f[0] * inv, f[1] * inv, f[2] * inv, f[3] * inv);
    float4 o1 = make_float4(f[4] * inv, f[5] * inv, f[6] * inv, f[7] * inv);
    *(float4*)(out + (size_t)w * 128 + sl * 8) = o0;
    *(float4*)(out + (size_t)w * 128 + sl * 8 + 4) = o1;
  }
}

// ---------------- launch ----------------
// ws layout (bytes):
//  xb  @ 0          [50048][320] bf16 = 32,030,720
//  W1b @ 32030720   [256][320]  bf16 =    163,840
//  W2b @ 32194560   [128][256]  bf16 =     65,536
//  h1  @ 32260096   [50048][256]bf16 = 25,624,576
//  h2  @ 57884672   [50048][256]bf16 = 25,624,576
//  h3  @ 83509248   [50048][128]bf16 = 12,812,288
//  ecv @ 96321536   800000 int2      =  6,400,000
//  rs  @ 102721536  50001 int        =    200,016
//  part@ 102921552  ~200 int (pad)
//  cur @ 102922368  50000 int        =    200,000
//  pos @ 103122368  800000 int       =  3,200,000   total ~106.3 MB

extern "C" void kernel_launch(void* const* d_in, const int* in_sizes, int n_in,
                              void* d_out, int out_size, void* d_ws, size_t ws_size,
                              hipStream_t stream){
  const float* x    = (const float*)d_in[0];
  const int*   erow = (const int*)d_in[1];
  const int*   ecol = (const int*)d_in[2];
  const float* evalv= (const float*)d_in[3];
  const float* W1   = (const float*)d_in[4];
  const float* b1   = (const float*)d_in[5];
  const float* W2   = (const float*)d_in[6];
  const float* b2   = (const float*)d_in[7];
  float* out = (float*)d_out;

  char* ws = (char*)d_ws;
  __bf16* xb  = (__bf16*)(ws);
  __bf16* W1b = (__bf16*)(ws + 32030720);
  __bf16* W2b = (__bf16*)(ws + 32194560);
  __bf16* h1  = (__bf16*)(ws + 32260096);
  __bf16* h2  = (__bf16*)(ws + 57884672);
  __bf16* h3  = (__bf16*)(ws + 83509248);
  int2*   ecv = (int2*)(ws + 96321536);
  int*    rs  = (int*)(ws + 102721536);
  int*    part= (int*)(ws + 102921552);
  int*    cur = (int*)(ws + 102922368);
  int*    pos = (int*)(ws + 103122368);   // dedicated storage (no alias)

  // 1) zero cur
  k_zero<<<196, 256, 0, stream>>>(cur);
  // 2) rank (latency-bound) overlapped with x/W conversions (BW-bound)
  rank_conv<<<17315, 256, 0, stream>>>(erow, cur, pos, x, W1, W2, xb, W1b, W2b);
  // 3-4) scan
  k_scan1<<<196, 256, 0, stream>>>(cur, rs, part, NN);
  k_scan3<<<196, 256, 0, stream>>>(rs, part, NN);
  // 5) scatter overlapped with gemm1 (h1 = bf16(xb @ W1b^T))
  scat_gemm<5, 2><<<3131, 256, 0, stream>>>(erow, ecol, evalv, rs, pos, ecv,
                                            xb, W1b, h1, 320, 256);
  // 6) h2 = bf16(relu(A*h1 + b1)), two 128-ch halves in one dispatch
  spmm_relu_b16<<<25000, 256, 0, stream>>>(ecv, rs, h1, b1, h2);
  // 7) h3 = bf16(h2 @ W2b^T)
  gemm_bf16<4, 1><<<784, 256, 0, stream>>>(h2, W2b, h3, 256, 128);
  // 8) out = l2norm(A*h3 + b2)
  spmm_bias_norm_b16<<<12500, 256, 0, stream>>>(ecv, rs, h3, b2, out);
}